// Round 1
// baseline (6431.725 us; speedup 1.0000x reference)
//
#include <hip/hip_runtime.h>
#include <hip/hip_bf16.h>
#include <math.h>

// Problem constants (B=2, L=1024 -> T=2048 tokens)
#define T_TOK 2048
#define Dd    2048
#define Ee    8
#define Kk    2
#define Hh    1408
#define HSs   2816

// ---------------------------------------------------------------------------
// init: zero per-expert counters (must run every call; ws is re-poisoned)
// ---------------------------------------------------------------------------
__global__ void init_cnt(int* __restrict__ cnt) {
    if (threadIdx.x < Ee) cnt[threadIdx.x] = 0;
}

// ---------------------------------------------------------------------------
// router: block per token. Computes 8 expert logits + shared sigmoid gate,
// top-2 with renormalized weights, appends (slot=t*2+k, weight) to the
// owning expert's list via atomics.
// ---------------------------------------------------------------------------
__global__ __launch_bounds__(256) void router_kernel(
    const float* __restrict__ x, const float* __restrict__ gate_w,
    const float* __restrict__ shgate_w,
    int* __restrict__ cnt, int* __restrict__ list_slot,
    float* __restrict__ list_w, float* __restrict__ sgate)
{
    const int t = blockIdx.x;
    const int tid = threadIdx.x;
    const float* xt = x + t * Dd;

    float acc[Ee];
#pragma unroll
    for (int e = 0; e < Ee; e++) acc[e] = 0.f;
    float accs = 0.f;

    for (int d = tid; d < Dd; d += 256) {
        float xv = xt[d];
#pragma unroll
        for (int e = 0; e < Ee; e++) acc[e] += xv * gate_w[e * Dd + d];
        accs += xv * shgate_w[d];
    }

    __shared__ float red[Ee + 1][256];
#pragma unroll
    for (int e = 0; e < Ee; e++) red[e][tid] = acc[e];
    red[Ee][tid] = accs;
    __syncthreads();

    for (int s = 128; s > 0; s >>= 1) {
        if (tid < s) {
#pragma unroll
            for (int e = 0; e <= Ee; e++) red[e][tid] += red[e][tid + s];
        }
        __syncthreads();
    }

    if (tid == 0) {
        // top-2 of logits (same order as softmax probs); lower index wins ties
        float l0 = -1e30f, l1 = -1e30f;
        int i0 = 0, i1 = 0;
#pragma unroll
        for (int e = 0; e < Ee; e++) {
            float v = red[e][0];
            if (v > l0) { l1 = l0; i1 = i0; l0 = v; i0 = e; }
            else if (v > l1) { l1 = v; i1 = e; }
        }
        // renormalized top-2 weights: softmax denom cancels
        float w0 = 1.f / (1.f + expf(l1 - l0));
        float w1 = 1.f - w0;

        int p0 = atomicAdd(&cnt[i0], 1);
        list_slot[i0 * T_TOK + p0] = t * 2 + 0;
        list_w  [i0 * T_TOK + p0] = w0;
        int p1 = atomicAdd(&cnt[i1], 1);
        list_slot[i1 * T_TOK + p1] = t * 2 + 1;
        list_w  [i1 * T_TOK + p1] = w1;

        sgate[t] = 1.f / (1.f + expf(-red[Ee][0]));
    }
}

// ---------------------------------------------------------------------------
// expert gate/up: grouped GEMM per expert. Tile: 32 gathered tokens x 64 h.
// hq[slot*H + h] = silu(x@w_gate) * (x@w_up)
// ---------------------------------------------------------------------------
__global__ __launch_bounds__(256) void expert_gateup(
    const float* __restrict__ x, const float* __restrict__ w_gate,
    const float* __restrict__ w_up, const int* __restrict__ cnt,
    const int* __restrict__ list_slot, float* __restrict__ hq)
{
    const int e  = blockIdx.z;
    const int n  = cnt[e];
    const int m0 = blockIdx.x * 32;
    if (m0 >= n) return;
    const int h0  = blockIdx.y * 64;
    const int tid = threadIdx.x;
    const int col = tid & 63;
    const int rg  = tid >> 6;  // 0..3

    __shared__ int   slots[32];
    __shared__ int   toks[32];
    __shared__ float xs[32][33];
    __shared__ float wg[32][64];
    __shared__ float wu[32][64];

    if (tid < 32) {
        int row = m0 + tid;
        int s = list_slot[e * T_TOK + (row < n ? row : n - 1)];
        slots[tid] = s;
        toks[tid]  = s >> 1;
    }
    __syncthreads();

    float accg[8], accu[8];
#pragma unroll
    for (int i = 0; i < 8; i++) { accg[i] = 0.f; accu[i] = 0.f; }

    for (int d0 = 0; d0 < Dd; d0 += 32) {
        __syncthreads();
#pragma unroll
        for (int j = 0; j < 4; j++) {
            int q = tid + j * 256;
            int r = q >> 5, c = q & 31;
            xs[r][c] = x[toks[r] * Dd + d0 + c];
        }
#pragma unroll
        for (int j = 0; j < 8; j++) {
            int q = tid + j * 256;
            int r = q >> 6, c = q & 63;
            int widx = (e * Dd + d0 + r) * Hh + h0 + c;
            wg[r][c] = w_gate[widx];
            wu[r][c] = w_up[widx];
        }
        __syncthreads();
#pragma unroll
        for (int kk = 0; kk < 32; kk++) {
            float gv = wg[kk][col];
            float uv = wu[kk][col];
#pragma unroll
            for (int i = 0; i < 8; i++) {
                float xv = xs[rg + 4 * i][kk];
                accg[i] += xv * gv;
                accu[i] += xv * uv;
            }
        }
    }

#pragma unroll
    for (int i = 0; i < 8; i++) {
        int row = rg + 4 * i;
        if (m0 + row < n) {
            float g = accg[i], u = accu[i];
            float s = g / (1.f + expf(-g));  // silu
            hq[slots[row] * Hh + h0 + col] = s * u;
        }
    }
}

// ---------------------------------------------------------------------------
// shared expert gate/up: dense GEMM, 32 tokens x 64 cols tiles.
// shh[t*HS + h] = silu(x@shw_gate) * (x@shw_up)
// ---------------------------------------------------------------------------
__global__ __launch_bounds__(256) void shared_gateup(
    const float* __restrict__ x, const float* __restrict__ shw_gate,
    const float* __restrict__ shw_up, float* __restrict__ shh)
{
    const int m0  = blockIdx.x * 32;
    const int h0  = blockIdx.y * 64;
    const int tid = threadIdx.x;
    const int col = tid & 63;
    const int rg  = tid >> 6;

    __shared__ float xs[32][33];
    __shared__ float wg[32][64];
    __shared__ float wu[32][64];

    float accg[8], accu[8];
#pragma unroll
    for (int i = 0; i < 8; i++) { accg[i] = 0.f; accu[i] = 0.f; }

    for (int d0 = 0; d0 < Dd; d0 += 32) {
        __syncthreads();
#pragma unroll
        for (int j = 0; j < 4; j++) {
            int q = tid + j * 256;
            int r = q >> 5, c = q & 31;
            xs[r][c] = x[(m0 + r) * Dd + d0 + c];
        }
#pragma unroll
        for (int j = 0; j < 8; j++) {
            int q = tid + j * 256;
            int r = q >> 6, c = q & 63;
            int widx = (d0 + r) * HSs + h0 + c;
            wg[r][c] = shw_gate[widx];
            wu[r][c] = shw_up[widx];
        }
        __syncthreads();
#pragma unroll
        for (int kk = 0; kk < 32; kk++) {
            float gv = wg[kk][col];
            float uv = wu[kk][col];
#pragma unroll
            for (int i = 0; i < 8; i++) {
                float xv = xs[rg + 4 * i][kk];
                accg[i] += xv * gv;
                accu[i] += xv * uv;
            }
        }
    }

#pragma unroll
    for (int i = 0; i < 8; i++) {
        int row = rg + 4 * i;
        float g = accg[i], u = accu[i];
        float s = g / (1.f + expf(-g));
        shh[(m0 + row) * HSs + h0 + col] = s * u;
    }
}

// ---------------------------------------------------------------------------
// shared expert down: out[t,d] = sgate[t] * (shh[t,:] @ shw_down[:,d])
// Plain store: covers every output element (initializes poisoned d_out).
// ---------------------------------------------------------------------------
__global__ __launch_bounds__(256) void shared_down(
    const float* __restrict__ shh, const float* __restrict__ shw_down,
    const float* __restrict__ sgate, float* __restrict__ out)
{
    const int m0  = blockIdx.x * 32;
    const int d0c = blockIdx.y * 64;
    const int tid = threadIdx.x;
    const int col = tid & 63;
    const int rg  = tid >> 6;

    __shared__ float as[32][33];
    __shared__ float bs[32][64];

    float acc[8];
#pragma unroll
    for (int i = 0; i < 8; i++) acc[i] = 0.f;

    for (int k0 = 0; k0 < HSs; k0 += 32) {
        __syncthreads();
#pragma unroll
        for (int j = 0; j < 4; j++) {
            int q = tid + j * 256;
            int r = q >> 5, c = q & 31;
            as[r][c] = shh[(m0 + r) * HSs + k0 + c];
        }
#pragma unroll
        for (int j = 0; j < 8; j++) {
            int q = tid + j * 256;
            int r = q >> 6, c = q & 63;
            bs[r][c] = shw_down[(k0 + r) * Dd + d0c + c];
        }
        __syncthreads();
#pragma unroll
        for (int kk = 0; kk < 32; kk++) {
            float bv = bs[kk][col];
#pragma unroll
            for (int i = 0; i < 8; i++) acc[i] += as[rg + 4 * i][kk] * bv;
        }
    }

#pragma unroll
    for (int i = 0; i < 8; i++) {
        int row = rg + 4 * i;
        out[(m0 + row) * Dd + d0c + col] = sgate[m0 + row] * acc[i];
    }
}

// ---------------------------------------------------------------------------
// expert down: grouped GEMM per expert; weighted atomicAdd into out.
// out[t,d] += w * (hq[slot,:] @ w_down[e,:,d])
// ---------------------------------------------------------------------------
__global__ __launch_bounds__(256) void expert_down(
    const float* __restrict__ hq, const float* __restrict__ w_down,
    const int* __restrict__ cnt, const int* __restrict__ list_slot,
    const float* __restrict__ list_w, float* __restrict__ out)
{
    const int e  = blockIdx.z;
    const int n  = cnt[e];
    const int m0 = blockIdx.x * 32;
    if (m0 >= n) return;
    const int d0c = blockIdx.y * 64;
    const int tid = threadIdx.x;
    const int col = tid & 63;
    const int rg  = tid >> 6;

    __shared__ int   slots[32];
    __shared__ int   toks[32];
    __shared__ float lw[32];
    __shared__ float as[32][33];
    __shared__ float bs[32][64];

    if (tid < 32) {
        int row = m0 + tid;
        int rr = row < n ? row : n - 1;
        int s = list_slot[e * T_TOK + rr];
        slots[tid] = s;
        toks[tid]  = s >> 1;
        lw[tid]    = row < n ? list_w[e * T_TOK + rr] : 0.f;
    }
    __syncthreads();

    float acc[8];
#pragma unroll
    for (int i = 0; i < 8; i++) acc[i] = 0.f;

    for (int k0 = 0; k0 < Hh; k0 += 32) {
        __syncthreads();
#pragma unroll
        for (int j = 0; j < 4; j++) {
            int q = tid + j * 256;
            int r = q >> 5, c = q & 31;
            as[r][c] = hq[slots[r] * Hh + k0 + c];
        }
#pragma unroll
        for (int j = 0; j < 8; j++) {
            int q = tid + j * 256;
            int r = q >> 6, c = q & 63;
            bs[r][c] = w_down[(e * Hh + k0 + r) * Dd + d0c + c];
        }
        __syncthreads();
#pragma unroll
        for (int kk = 0; kk < 32; kk++) {
            float bv = bs[kk][col];
#pragma unroll
            for (int i = 0; i < 8; i++) acc[i] += as[rg + 4 * i][kk] * bv;
        }
    }

#pragma unroll
    for (int i = 0; i < 8; i++) {
        int row = rg + 4 * i;
        if (m0 + row < n) {
            atomicAdd(&out[toks[row] * Dd + d0c + col], lw[row] * acc[i]);
        }
    }
}

// ---------------------------------------------------------------------------
// launch
// ---------------------------------------------------------------------------
extern "C" void kernel_launch(void* const* d_in, const int* in_sizes, int n_in,
                              void* d_out, int out_size, void* d_ws, size_t ws_size,
                              hipStream_t stream) {
    const float* x        = (const float*)d_in[0];
    const float* gate_w   = (const float*)d_in[1];
    const float* w_gate   = (const float*)d_in[2];
    const float* w_up     = (const float*)d_in[3];
    const float* w_down   = (const float*)d_in[4];
    const float* shgate_w = (const float*)d_in[5];
    const float* shw_gate = (const float*)d_in[6];
    const float* shw_up   = (const float*)d_in[7];
    const float* shw_down = (const float*)d_in[8];
    float* out = (float*)d_out;

    // workspace layout
    char* ws = (char*)d_ws;
    int*   cnt       = (int*)(ws);                       // 8 ints
    int*   list_slot = (int*)(ws + 256);                 // E*T ints  (64 KB)
    float* list_w    = (float*)(ws + 256 + 65536);       // E*T float (64 KB)
    float* sgate     = (float*)(ws + 256 + 131072);      // T float   (8 KB)
    float* hq        = (float*)(ws + 256 + 131072 + 8192);          // T*K*H fp32 (23.1 MB)
    float* shh       = hq + (size_t)T_TOK * Kk * Hh;                 // T*HS fp32  (23.1 MB)

    init_cnt<<<dim3(1), dim3(64), 0, stream>>>(cnt);
    router_kernel<<<dim3(T_TOK), dim3(256), 0, stream>>>(
        x, gate_w, shgate_w, cnt, list_slot, list_w, sgate);
    expert_gateup<<<dim3(T_TOK / 32, Hh / 64, Ee), dim3(256), 0, stream>>>(
        x, w_gate, w_up, cnt, list_slot, hq);
    shared_gateup<<<dim3(T_TOK / 32, HSs / 64), dim3(256), 0, stream>>>(
        x, shw_gate, shw_up, shh);
    shared_down<<<dim3(T_TOK / 32, Dd / 64), dim3(256), 0, stream>>>(
        shh, shw_down, sgate, out);
    expert_down<<<dim3(T_TOK / 32, Dd / 64, Ee), dim3(256), 0, stream>>>(
        hq, w_down, cnt, list_slot, list_w, out);
}

// Round 2
// 763.179 us; speedup vs baseline: 8.4275x; 8.4275x over previous
//
#include <hip/hip_runtime.h>
#include <hip/hip_bf16.h>
#include <math.h>

// Problem constants (B=2, L=1024 -> T=2048 tokens)
#define T_TOK 2048
#define Dd    2048
#define Ee    8
#define Hh    1408
#define HSs   2816
#define CAP   1024   // per-expert token capacity (mean 512, sigma ~21 -> 24 sigma)

typedef __attribute__((ext_vector_type(8))) __bf16 bf16x8;
typedef __attribute__((ext_vector_type(4))) __bf16 bf16x4;
typedef __attribute__((ext_vector_type(4))) float  f32x4;

#define MFMA(a, b, c) __builtin_amdgcn_mfma_f32_16x16x32_bf16(a, b, c, 0, 0, 0)

// async global->LDS 16B/lane copy (lane-contiguous LDS dest required)
__device__ __forceinline__ void async_copy16(const __bf16* g, __bf16* l) {
    __builtin_amdgcn_global_load_lds(
        (const __attribute__((address_space(1))) unsigned int*)g,
        (__attribute__((address_space(3))) unsigned int*)l, 16, 0, 0);
}

// ---------------------------------------------------------------------------
// init: zero per-expert counters
// ---------------------------------------------------------------------------
__global__ void init_cnt(int* __restrict__ cnt) {
    if (threadIdx.x < Ee) cnt[threadIdx.x] = 0;
}

// ---------------------------------------------------------------------------
// router (fp32): logits, top-2 renorm weights, packed per-expert lists,
// shared-expert sigmoid gate
// ---------------------------------------------------------------------------
__global__ __launch_bounds__(256) void router_kernel(
    const float* __restrict__ x, const float* __restrict__ gate_w,
    const float* __restrict__ shgate_w,
    int* __restrict__ cnt, int* __restrict__ ptok,
    float* __restrict__ pw, float* __restrict__ sgate)
{
    const int t = blockIdx.x;
    const int tid = threadIdx.x;
    const float* xt = x + (size_t)t * Dd;

    float acc[Ee];
#pragma unroll
    for (int e = 0; e < Ee; e++) acc[e] = 0.f;
    float accs = 0.f;

    for (int d = tid; d < Dd; d += 256) {
        float xv = xt[d];
#pragma unroll
        for (int e = 0; e < Ee; e++) acc[e] += xv * gate_w[e * Dd + d];
        accs += xv * shgate_w[d];
    }

    __shared__ float red[Ee + 1][256];
#pragma unroll
    for (int e = 0; e < Ee; e++) red[e][tid] = acc[e];
    red[Ee][tid] = accs;
    __syncthreads();

    for (int s = 128; s > 0; s >>= 1) {
        if (tid < s) {
#pragma unroll
            for (int e = 0; e <= Ee; e++) red[e][tid] += red[e][tid + s];
        }
        __syncthreads();
    }

    if (tid == 0) {
        float l0 = -1e30f, l1 = -1e30f;
        int i0 = 0, i1 = 0;
#pragma unroll
        for (int e = 0; e < Ee; e++) {
            float v = red[e][0];
            if (v > l0) { l1 = l0; i1 = i0; l0 = v; i0 = e; }
            else if (v > l1) { l1 = v; i1 = e; }
        }
        float w0 = 1.f / (1.f + expf(l1 - l0));  // renormalized top-2
        float w1 = 1.f - w0;

        int p0 = atomicAdd(&cnt[i0], 1);
        if (p0 < CAP) { ptok[i0 * CAP + p0] = t; pw[i0 * CAP + p0] = w0; }
        int p1 = atomicAdd(&cnt[i1], 1);
        if (p1 < CAP) { ptok[i1 * CAP + p1] = t; pw[i1 * CAP + p1] = w1; }

        sgate[t] = 1.f / (1.f + expf(-red[Ee][0]));
    }
}

// ---------------------------------------------------------------------------
// cvt_x: fp32 -> bf16 straight copy of x (16B loads, 8B stores)
// ---------------------------------------------------------------------------
__global__ __launch_bounds__(256) void cvt_x(const float* __restrict__ src,
                                             __bf16* __restrict__ dst)
{
    int i = blockIdx.x * 256 + threadIdx.x;  // i < T*D/4
    float4 v = ((const float4*)src)[i];
    bf16x4 o = { (__bf16)v.x, (__bf16)v.y, (__bf16)v.z, (__bf16)v.w };
    ((bf16x4*)dst)[i] = o;
}

// ---------------------------------------------------------------------------
// transpose_cvt: src fp32 [R][C] (batched) -> dst bf16 [C][R]
// grid (C/32, R/32, batch), block (32, 8)
// ---------------------------------------------------------------------------
__global__ __launch_bounds__(256) void transpose_cvt(
    const float* __restrict__ src, __bf16* __restrict__ dst, int R, int C)
{
    const size_t bstride = (size_t)R * C;
    src += blockIdx.z * bstride;
    dst += blockIdx.z * bstride;
    __shared__ float tile[32][33];
    const int tx = threadIdx.x, ty = threadIdx.y;
    const int c0 = blockIdx.x * 32, r0 = blockIdx.y * 32;
#pragma unroll
    for (int j = 0; j < 4; j++)
        tile[ty + 8 * j][tx] = src[(size_t)(r0 + ty + 8 * j) * C + c0 + tx];
    __syncthreads();
#pragma unroll
    for (int j = 0; j < 4; j++)
        dst[(size_t)(c0 + ty + 8 * j) * R + r0 + tx] = (__bf16)tile[tx][ty + 8 * j];
}

// ---------------------------------------------------------------------------
// gateup (expert): C[128 tok x 64 h] for BOTH gate and up, fused silu*u.
// A = xb gathered rows (bf16 [T][D]); B = wgT/wuT bf16 [E][H][D] (k-contig).
// grid (E*8, H/64). Wave w owns rows [32w,32w+32) x all 64 cols.
// ---------------------------------------------------------------------------
__global__ __launch_bounds__(256, 3) void gateup_expert(
    const __bf16* __restrict__ xb,
    const __bf16* __restrict__ wgT, const __bf16* __restrict__ wuT,
    const int* __restrict__ cnt, const int* __restrict__ ptok,
    __bf16* __restrict__ hq)
{
    const int e = blockIdx.x >> 3, mt = blockIdx.x & 7;
    int n = cnt[e]; if (n > CAP) n = CAP;
    const int m0 = mt * 128;
    if (m0 >= n) return;
    const int h0 = blockIdx.y * 64;
    const int tid = threadIdx.x, lane = tid & 63, wave = tid >> 6;

    __shared__ __align__(16) __bf16 As[128 * 32];
    __shared__ __align__(16) __bf16 Bgs[64 * 32];
    __shared__ __align__(16) __bf16 Bus[64 * 32];
    __shared__ int tok_s[128];

    if (tid < 128) {
        int i = m0 + tid; int ic = i < n ? i : n - 1;
        tok_s[tid] = ptok[e * CAP + ic];
    }
    __syncthreads();

    const int kq = (tid & 3) * 8;       // 8-elem k offset within 32-k tile
    const int r1 = tid >> 2, r2 = 64 + (tid >> 2);
    const __bf16* ga1 = xb + (size_t)tok_s[r1] * Dd + kq;
    const __bf16* ga2 = xb + (size_t)tok_s[r2] * Dd + kq;
    const size_t wbase = (size_t)e * Hh * Dd + (size_t)(h0 + (tid >> 2)) * Dd + kq;
    const __bf16* gbg = wgT + wbase;
    const __bf16* gbu = wuT + wbase;
    __bf16* la1 = As + tid * 8; __bf16* la2 = As + (tid + 256) * 8;
    __bf16* lbg = Bgs + tid * 8; __bf16* lbu = Bus + tid * 8;

    f32x4 accg[2][4] = {}, accu[2][4] = {};
    const int q = lane >> 4, m = lane & 15;

    for (int k0 = 0; k0 < Dd; k0 += 32) {
        async_copy16(ga1 + k0, la1);
        async_copy16(ga2 + k0, la2);
        async_copy16(gbg + k0, lbg);
        async_copy16(gbu + k0, lbu);
        __syncthreads();
        bf16x8 af[2], bgf[4], buf_[4];
        af[0] = *(const bf16x8*)(As + (wave * 32 + m) * 32 + q * 8);
        af[1] = *(const bf16x8*)(As + (wave * 32 + 16 + m) * 32 + q * 8);
#pragma unroll
        for (int j = 0; j < 4; j++) {
            bgf[j]  = *(const bf16x8*)(Bgs + (j * 16 + m) * 32 + q * 8);
            buf_[j] = *(const bf16x8*)(Bus + (j * 16 + m) * 32 + q * 8);
        }
#pragma unroll
        for (int i = 0; i < 2; i++)
#pragma unroll
            for (int j = 0; j < 4; j++) {
                accg[i][j] = MFMA(af[i], bgf[j], accg[i][j]);
                accu[i][j] = MFMA(af[i], buf_[j], accu[i][j]);
            }
        __syncthreads();
    }

#pragma unroll
    for (int i = 0; i < 2; i++)
#pragma unroll
        for (int r = 0; r < 4; r++) {
            int row = wave * 32 + i * 16 + q * 4 + r;
            size_t p = (size_t)(e * CAP + m0 + row);
#pragma unroll
            for (int j = 0; j < 4; j++) {
                int h = h0 + j * 16 + m;
                float g = accg[i][j][r], u = accu[i][j][r];
                float s = g / (1.f + __expf(-g));
                hq[p * Hh + h] = (__bf16)(s * u);
            }
        }
}

// ---------------------------------------------------------------------------
// gateup (shared): dense version. A = xb [T][D]; B = shwgT/shwuT [HS][D].
// grid (T/128, HS/64). Writes shh bf16 [T][HS].
// ---------------------------------------------------------------------------
__global__ __launch_bounds__(256, 3) void gateup_shared(
    const __bf16* __restrict__ xb,
    const __bf16* __restrict__ wgT, const __bf16* __restrict__ wuT,
    __bf16* __restrict__ shh)
{
    const int m0 = blockIdx.x * 128;
    const int h0 = blockIdx.y * 64;
    const int tid = threadIdx.x, lane = tid & 63, wave = tid >> 6;

    __shared__ __align__(16) __bf16 As[128 * 32];
    __shared__ __align__(16) __bf16 Bgs[64 * 32];
    __shared__ __align__(16) __bf16 Bus[64 * 32];

    const int kq = (tid & 3) * 8;
    const __bf16* ga1 = xb + (size_t)(m0 + (tid >> 2)) * Dd + kq;
    const __bf16* ga2 = xb + (size_t)(m0 + 64 + (tid >> 2)) * Dd + kq;
    const size_t wbase = (size_t)(h0 + (tid >> 2)) * Dd + kq;
    const __bf16* gbg = wgT + wbase;
    const __bf16* gbu = wuT + wbase;
    __bf16* la1 = As + tid * 8; __bf16* la2 = As + (tid + 256) * 8;
    __bf16* lbg = Bgs + tid * 8; __bf16* lbu = Bus + tid * 8;

    f32x4 accg[2][4] = {}, accu[2][4] = {};
    const int q = lane >> 4, m = lane & 15;

    for (int k0 = 0; k0 < Dd; k0 += 32) {
        async_copy16(ga1 + k0, la1);
        async_copy16(ga2 + k0, la2);
        async_copy16(gbg + k0, lbg);
        async_copy16(gbu + k0, lbu);
        __syncthreads();
        bf16x8 af[2], bgf[4], buf_[4];
        af[0] = *(const bf16x8*)(As + (wave * 32 + m) * 32 + q * 8);
        af[1] = *(const bf16x8*)(As + (wave * 32 + 16 + m) * 32 + q * 8);
#pragma unroll
        for (int j = 0; j < 4; j++) {
            bgf[j]  = *(const bf16x8*)(Bgs + (j * 16 + m) * 32 + q * 8);
            buf_[j] = *(const bf16x8*)(Bus + (j * 16 + m) * 32 + q * 8);
        }
#pragma unroll
        for (int i = 0; i < 2; i++)
#pragma unroll
            for (int j = 0; j < 4; j++) {
                accg[i][j] = MFMA(af[i], bgf[j], accg[i][j]);
                accu[i][j] = MFMA(af[i], buf_[j], accu[i][j]);
            }
        __syncthreads();
    }

#pragma unroll
    for (int i = 0; i < 2; i++)
#pragma unroll
        for (int r = 0; r < 4; r++) {
            int row = wave * 32 + i * 16 + q * 4 + r;
#pragma unroll
            for (int j = 0; j < 4; j++) {
                int h = h0 + j * 16 + m;
                float g = accg[i][j][r], u = accu[i][j][r];
                float s = g / (1.f + __expf(-g));
                shh[(size_t)(m0 + row) * HSs + h] = (__bf16)(s * u);
            }
        }
}

// ---------------------------------------------------------------------------
// down (shared): out[t][d] = sgate[t] * (shh[t,:] @ shw_down[:,d]).
// m97-style 128x128, waves 2x2 each 64x64. Plain store = full out coverage.
// ---------------------------------------------------------------------------
__global__ __launch_bounds__(256, 3) void down_shared(
    const __bf16* __restrict__ A,      // shh [T][HS]
    const __bf16* __restrict__ BT,     // shwdT [D][HS]
    const float* __restrict__ sgate,
    float* __restrict__ out)
{
    const int m0 = blockIdx.x * 128, n0 = blockIdx.y * 128;
    const int tid = threadIdx.x, lane = tid & 63, wave = tid >> 6;
    const int wr = wave >> 1, wc = wave & 1;

    __shared__ __align__(16) __bf16 As[128 * 32];
    __shared__ __align__(16) __bf16 Bs[128 * 32];

    const int kq = (tid & 3) * 8;
    const __bf16* ga1 = A + (size_t)(m0 + (tid >> 2)) * HSs + kq;
    const __bf16* ga2 = A + (size_t)(m0 + 64 + (tid >> 2)) * HSs + kq;
    const __bf16* gb1 = BT + (size_t)(n0 + (tid >> 2)) * HSs + kq;
    const __bf16* gb2 = BT + (size_t)(n0 + 64 + (tid >> 2)) * HSs + kq;
    __bf16* la1 = As + tid * 8; __bf16* la2 = As + (tid + 256) * 8;
    __bf16* lb1 = Bs + tid * 8; __bf16* lb2 = Bs + (tid + 256) * 8;

    f32x4 acc[4][4] = {};
    const int q = lane >> 4, m = lane & 15;

    for (int k0 = 0; k0 < HSs; k0 += 32) {
        async_copy16(ga1 + k0, la1);
        async_copy16(ga2 + k0, la2);
        async_copy16(gb1 + k0, lb1);
        async_copy16(gb2 + k0, lb2);
        __syncthreads();
        bf16x8 af[4], bf[4];
#pragma unroll
        for (int i = 0; i < 4; i++) {
            af[i] = *(const bf16x8*)(As + (wr * 64 + i * 16 + m) * 32 + q * 8);
            bf[i] = *(const bf16x8*)(Bs + (wc * 64 + i * 16 + m) * 32 + q * 8);
        }
#pragma unroll
        for (int i = 0; i < 4; i++)
#pragma unroll
            for (int j = 0; j < 4; j++)
                acc[i][j] = MFMA(af[i], bf[j], acc[i][j]);
        __syncthreads();
    }

#pragma unroll
    for (int i = 0; i < 4; i++)
#pragma unroll
        for (int r = 0; r < 4; r++) {
            int t = m0 + wr * 64 + i * 16 + q * 4 + r;
            float sg = sgate[t];
#pragma unroll
            for (int j = 0; j < 4; j++) {
                int d = n0 + wc * 64 + j * 16 + m;
                out[(size_t)t * Dd + d] = sg * acc[i][j][r];
            }
        }
}

// ---------------------------------------------------------------------------
// down (expert): acc = hq[packed rows] @ w_down; scatter
// out[tok][d] += w * acc via atomicAdd. grid (E*8, D/128).
// ---------------------------------------------------------------------------
__global__ __launch_bounds__(256, 3) void down_expert(
    const __bf16* __restrict__ hq,     // [E*CAP][H]
    const __bf16* __restrict__ wdT,    // [E][D][H]
    const int* __restrict__ cnt, const int* __restrict__ ptok,
    const float* __restrict__ pw,
    float* __restrict__ out)
{
    const int e = blockIdx.x >> 3, mt = blockIdx.x & 7;
    int n = cnt[e]; if (n > CAP) n = CAP;
    const int m0 = mt * 128;
    if (m0 >= n) return;
    const int n0 = blockIdx.y * 128;
    const int tid = threadIdx.x, lane = tid & 63, wave = tid >> 6;
    const int wr = wave >> 1, wc = wave & 1;

    __shared__ __align__(16) __bf16 As[128 * 32];
    __shared__ __align__(16) __bf16 Bs[128 * 32];
    __shared__ int   tok_s[128];
    __shared__ float w_s[128];

    if (tid < 128) {
        int i = m0 + tid; int ic = i < n ? i : n - 1;
        tok_s[tid] = ptok[e * CAP + ic];
        w_s[tid] = (i < n) ? pw[e * CAP + ic] : 0.f;
    }

    const int kq = (tid & 3) * 8;
    int i1 = m0 + (tid >> 2);       if (i1 > n - 1) i1 = n - 1;
    int i2 = m0 + 64 + (tid >> 2);  if (i2 > n - 1) i2 = n - 1;
    const __bf16* ga1 = hq + (size_t)(e * CAP + i1) * Hh + kq;
    const __bf16* ga2 = hq + (size_t)(e * CAP + i2) * Hh + kq;
    const __bf16* gb1 = wdT + ((size_t)e * Dd + n0 + (tid >> 2)) * Hh + kq;
    const __bf16* gb2 = wdT + ((size_t)e * Dd + n0 + 64 + (tid >> 2)) * Hh + kq;
    __bf16* la1 = As + tid * 8; __bf16* la2 = As + (tid + 256) * 8;
    __bf16* lb1 = Bs + tid * 8; __bf16* lb2 = Bs + (tid + 256) * 8;

    f32x4 acc[4][4] = {};
    const int q = lane >> 4, m = lane & 15;

    for (int k0 = 0; k0 < Hh; k0 += 32) {
        async_copy16(ga1 + k0, la1);
        async_copy16(ga2 + k0, la2);
        async_copy16(gb1 + k0, lb1);
        async_copy16(gb2 + k0, lb2);
        __syncthreads();
        bf16x8 af[4], bf[4];
#pragma unroll
        for (int i = 0; i < 4; i++) {
            af[i] = *(const bf16x8*)(As + (wr * 64 + i * 16 + m) * 32 + q * 8);
            bf[i] = *(const bf16x8*)(Bs + (wc * 64 + i * 16 + m) * 32 + q * 8);
        }
#pragma unroll
        for (int i = 0; i < 4; i++)
#pragma unroll
            for (int j = 0; j < 4; j++)
                acc[i][j] = MFMA(af[i], bf[j], acc[i][j]);
        __syncthreads();
    }

#pragma unroll
    for (int i = 0; i < 4; i++)
#pragma unroll
        for (int r = 0; r < 4; r++) {
            int row = wr * 64 + i * 16 + q * 4 + r;
            if (m0 + row < n) {
                int   tok = tok_s[row];
                float w   = w_s[row];
#pragma unroll
                for (int j = 0; j < 4; j++) {
                    int d = n0 + wc * 64 + j * 16 + m;
                    atomicAdd(&out[(size_t)tok * Dd + d], w * acc[i][j][r]);
                }
            }
        }
}

// ---------------------------------------------------------------------------
// launch
// ---------------------------------------------------------------------------
extern "C" void kernel_launch(void* const* d_in, const int* in_sizes, int n_in,
                              void* d_out, int out_size, void* d_ws, size_t ws_size,
                              hipStream_t stream) {
    const float* x        = (const float*)d_in[0];
    const float* gate_w   = (const float*)d_in[1];
    const float* w_gate   = (const float*)d_in[2];
    const float* w_up     = (const float*)d_in[3];
    const float* w_down   = (const float*)d_in[4];
    const float* shgate_w = (const float*)d_in[5];
    const float* shw_gate = (const float*)d_in[6];
    const float* shw_up   = (const float*)d_in[7];
    const float* shw_down = (const float*)d_in[8];
    float* out = (float*)d_out;

    // ---- workspace layout (bytes, 256-aligned) ----
    char* ws = (char*)d_ws;
    size_t off = 0;
    auto alloc = [&](size_t bytes) { char* p = ws + off; off = (off + bytes + 255) & ~(size_t)255; return p; };
    int*    cnt    = (int*)   alloc(Ee * 4);
    int*    ptok   = (int*)   alloc(Ee * CAP * 4);
    float*  pw     = (float*) alloc(Ee * CAP * 4);
    float*  sgate  = (float*) alloc(T_TOK * 4);
    __bf16* xb     = (__bf16*)alloc((size_t)T_TOK * Dd * 2);
    __bf16* wgT    = (__bf16*)alloc((size_t)Ee * Hh * Dd * 2);
    __bf16* wuT    = (__bf16*)alloc((size_t)Ee * Hh * Dd * 2);
    __bf16* wdT    = (__bf16*)alloc((size_t)Ee * Dd * Hh * 2);
    __bf16* shwgT  = (__bf16*)alloc((size_t)HSs * Dd * 2);
    __bf16* shwuT  = (__bf16*)alloc((size_t)HSs * Dd * 2);
    __bf16* shwdT  = (__bf16*)alloc((size_t)Dd * HSs * 2);
    __bf16* hq     = (__bf16*)alloc((size_t)Ee * CAP * Hh * 2);
    __bf16* shh    = (__bf16*)alloc((size_t)T_TOK * HSs * 2);

    dim3 b256(256), bT(32, 8);

    init_cnt<<<dim3(1), dim3(64), 0, stream>>>(cnt);
    cvt_x<<<dim3(T_TOK * Dd / 4 / 256), b256, 0, stream>>>(x, xb);
    // weight transposes: src [R][C] fp32 -> dst [C][R] bf16
    transpose_cvt<<<dim3(Hh / 32, Dd / 32, Ee), bT, 0, stream>>>(w_gate, wgT, Dd, Hh);
    transpose_cvt<<<dim3(Hh / 32, Dd / 32, Ee), bT, 0, stream>>>(w_up, wuT, Dd, Hh);
    transpose_cvt<<<dim3(Dd / 32, Hh / 32, Ee), bT, 0, stream>>>(w_down, wdT, Hh, Dd);
    transpose_cvt<<<dim3(HSs / 32, Dd / 32, 1), bT, 0, stream>>>(shw_gate, shwgT, Dd, HSs);
    transpose_cvt<<<dim3(HSs / 32, Dd / 32, 1), bT, 0, stream>>>(shw_up, shwuT, Dd, HSs);
    transpose_cvt<<<dim3(Dd / 32, HSs / 32, 1), bT, 0, stream>>>(shw_down, shwdT, HSs, Dd);

    router_kernel<<<dim3(T_TOK), b256, 0, stream>>>(x, gate_w, shgate_w, cnt, ptok, pw, sgate);

    gateup_expert<<<dim3(Ee * 8, Hh / 64), b256, 0, stream>>>(xb, wgT, wuT, cnt, ptok, hq);
    gateup_shared<<<dim3(T_TOK / 128, HSs / 64), b256, 0, stream>>>(xb, shwgT, shwuT, shh);
    down_shared<<<dim3(T_TOK / 128, Dd / 128), b256, 0, stream>>>(shh, shwdT, sgate, out);
    down_expert<<<dim3(Ee * 8, Dd / 128), b256, 0, stream>>>(hq, wdT, cnt, ptok, pw, out);
}